// Round 10
// baseline (161.798 us; speedup 1.0000x reference)
//
#include <hip/hip_runtime.h>
#include <hip/hip_bf16.h>
#include <math.h>

#define T_TOK 8192
#define D_MODEL 2048
#define N_EXP 16
#define CAP 512
#define NSEG (T_TOK / 64)           // 128

// ws layout (bytes):
// aff:   0       .. 524288    (unused; layout stability)
// pref:  524288  .. +65536    u64[T_TOK]
// probs: 589824  .. +524288   float[T_TOK][16]
// evt:   1114112 .. +128      int[32] (evp[16], evf[16])
// gsync: 1114240 .. +8192     int[2] grid-barrier counters (armed by K1 each iteration)
// bcnt:  1122432 .. +2048     int[16][16]

__device__ __forceinline__ unsigned int f2ord(float f) {
    unsigned int b = __float_as_uint(f);
    return (b & 0x80000000u) ? ~b : (b | 0x80000000u);
}

// direct global->LDS DMA, 16 B per lane, no VGPR round-trip
#define GLOBAL_LOAD_LDS16(g, l)                                            \
    __builtin_amdgcn_global_load_lds(                                      \
        (const __attribute__((address_space(1))) unsigned int*)(g),        \
        (__attribute__((address_space(3))) unsigned int*)(l), 16, 0, 0)

// read a u64 register from a (uniform) lane as a scalar — no ds_bpermute
__device__ __forceinline__ unsigned long long rdlane64(unsigned long long v, int l) {
    unsigned int lo = (unsigned int)__builtin_amdgcn_readlane((int)(unsigned int)(v & 0xFFFFFFFFull), l);
    unsigned int hi = (unsigned int)__builtin_amdgcn_readlane((int)(unsigned int)(v >> 32), l);
    return ((unsigned long long)hi << 32) | (unsigned long long)lo;
}

// wave64 inclusive int scan: 4 DPP row_shr adds (intra-row16) + readlane fixups.
__device__ __forceinline__ int wave_incl_scan(int x, int lane) {
    x += __builtin_amdgcn_update_dpp(0, x, 0x111, 0xF, 0xF, false);  // row_shr:1
    x += __builtin_amdgcn_update_dpp(0, x, 0x112, 0xF, 0xF, false);  // row_shr:2
    x += __builtin_amdgcn_update_dpp(0, x, 0x114, 0xF, 0xF, false);  // row_shr:4
    x += __builtin_amdgcn_update_dpp(0, x, 0x118, 0xF, 0xF, false);  // row_shr:8
    const int r15 = __builtin_amdgcn_readlane(x, 15);   // row0 total
    const int r47 = __builtin_amdgcn_readlane(x, 47);   // row2 total
    const int grp = lane & 48;
    if (grp == 16) x += r15;          // row1 += row0
    else if (grp == 48) x += r47;     // row3 += row2
    const int r31 = __builtin_amdgcn_readlane(x, 31);   // rows0+1 total
    if (lane >= 32) x += r31;         // upper half += lower-half total
    return x;
}

// ---------------- Kernel 1: GEMM + fused finalize (verified r8, verbatim) ----------------
__global__ __launch_bounds__(512) void gemm_finalize_kernel(
    const float* __restrict__ feat, const float* __restrict__ W,
    const float* __restrict__ bias,
    unsigned long long* __restrict__ pref, float* __restrict__ probs,
    int* __restrict__ gsync)
{
    __shared__ float flds[8][D_MODEL];   // 64 KiB
    __shared__ float afft[8][N_EXP];     // 512 B

    const int tid  = threadIdx.x;
    const int wave = tid >> 6, lane = tid & 63;
    const int tbase = blockIdx.x * 8;

    if (blockIdx.x == 0 && tid == 0) { gsync[0] = 0; gsync[1] = 0; }

    {
        const float* src = feat + (size_t)tbase * D_MODEL;
        #pragma unroll
        for (int i = 0; i < 8; ++i) {
            const int idx = tid + i * 512;           // float4 index
            GLOBAL_LOAD_LDS16(src + (size_t)idx * 4, &flds[0][0] + (size_t)idx * 4);
        }
    }

    const float* w0 = W + (size_t)(wave * 2) * D_MODEL + lane * 4;
    const float* w1 = w0 + D_MODEL;

    float acc[16];
    #pragma unroll
    for (int i = 0; i < 16; ++i) acc[i] = 0.f;

    __syncthreads();   // drains the global_load_lds queue (vmcnt)

    #pragma unroll 1
    for (int j = 0; j < 8; ++j) {               // 8 k-chunks of 256 floats
        const float4 wv0 = *(const float4*)(w0 + j * 256);
        const float4 wv1 = *(const float4*)(w1 + j * 256);
        const float* fl = &flds[0][0] + j * 256 + lane * 4;
        #pragma unroll
        for (int r = 0; r < 8; ++r) {
            float4 f = *(const float4*)(fl + r * D_MODEL);
            acc[r * 2 + 0] += f.x * wv0.x;
            acc[r * 2 + 0] += f.y * wv0.y;
            acc[r * 2 + 0] += f.z * wv0.z;
            acc[r * 2 + 0] += f.w * wv0.w;
            acc[r * 2 + 1] += f.x * wv1.x;
            acc[r * 2 + 1] += f.y * wv1.y;
            acc[r * 2 + 1] += f.z * wv1.z;
            acc[r * 2 + 1] += f.w * wv1.w;
        }
    }

    #pragma unroll
    for (int step = 0; step < 4; ++step) {
        const int m    = 1 << step;
        const int half = 8 >> step;
        const bool hi  = (lane & m) != 0;
        #pragma unroll
        for (int jj = 0; jj < half; ++jj) {
            float send = hi ? acc[jj] : acc[jj + half];
            float recv = __shfl_xor(send, m, 64);
            acc[jj] = (hi ? acc[jj + half] : acc[jj]) + recv;
        }
    }
    acc[0] += __shfl_xor(acc[0], 16, 64);
    acc[0] += __shfl_xor(acc[0], 32, 64);

    if (lane < 16) {
        const int slot = ((lane & 1) << 3) | (((lane >> 1) & 1) << 2)
                       | (((lane >> 2) & 1) << 1) | ((lane >> 3) & 1);
        const int r = slot >> 1, el = slot & 1;
        afft[r][wave * 2 + el] = acc[0];
    }
    __syncthreads();

    const int tk = tbase + wave;
    const int j  = lane & 15;
    float v = afft[wave][j] + bias[j];

    float mx = v;
    #pragma unroll
    for (int d = 1; d < 16; d <<= 1)
        mx = fmaxf(mx, __shfl_xor(mx, d, 16));

    float ex = __expf(v - mx);

    float s = 0.f;
    #pragma unroll
    for (int e2 = 0; e2 < N_EXP; ++e2)
        s += __shfl(ex, e2, 16);

    if (lane < 16)
        probs[(size_t)tk * N_EXP + lane] = ex / s;

    unsigned long long key = ((unsigned long long)f2ord(v) << 4)
                           | (unsigned long long)(15 - j);
    int rank = 0;
    #pragma unroll
    for (int d = 1; d < 16; ++d) {
        unsigned long long o = __shfl_xor(key, d, 16);
        rank += (o > key) ? 1 : 0;
    }
    unsigned long long contrib = ((unsigned long long)j) << (4 * (15 - rank));
    #pragma unroll
    for (int d = 1; d < 16; d <<= 1)
        contrib |= __shfl_xor(contrib, d, 16);
    if (lane == 0)
        pref[tk] = contrib;
}

// ---------------- Kernel 2: events (block 0) + choice + writeout + clock-hold burners ----------------
// Blocks 0-15: verified r6/r8 worker code, verbatim (all computed values identical).
// Blocks 16-255: MAX-DOSE burners (~94% of CUs at full VALU) — dose-response test of the
// clock theory (r9's 12% dose was null; events ran 43-50us whenever preceded by a heavy
// ~50us dispatch, 75-85us when preceded by the lean 10us K1, code identical). Burners poll
// the barrier-1 counter (reaches 16 exactly when events completes) once per ~0.9us via one
// device-scope atomic per block, hard-capped (no hang), exit before choice/write.
__global__ __launch_bounds__(512, 1) void events_choice_write_kernel(
    const unsigned long long* __restrict__ pref, const float* __restrict__ probs,
    int* __restrict__ evt, int* __restrict__ gsync, int* __restrict__ bcnt,
    float* __restrict__ out0, float* __restrict__ out1)
{
    __shared__ unsigned long long segmask[N_EXP][NSEG];   // 16 KB
    __shared__ int fparr[N_EXP];
    __shared__ int evp[N_EXP], evf[N_EXP];
    __shared__ int sc[8][N_EXP];
    __shared__ int base[N_EXP];
    __shared__ int pcnt[16][N_EXP];

    const int tid  = threadIdx.x;
    const int wave = tid >> 6, lane = tid & 63;
    const unsigned long long lt_mask = (1ull << lane) - 1ull;
    const int b = blockIdx.x;

    if (b >= 16) {
        // ---- burner: 8 independent dependent-FMA chains, rare polls, bounded ----
        float x0 = (float)tid * 0.5f + 1.0f;
        float x1 = x0 + 0.125f, x2 = x0 + 0.25f, x3 = x0 + 0.375f;
        float x4 = x0 + 0.5f,   x5 = x0 + 0.625f, x6 = x0 + 0.75f, x7 = x0 + 0.875f;
        const float aa = 1.0000001f, cc = 0.9999999f;
        for (int outer = 0; outer < 512; ++outer) {      // hard cap (~<450us worst-case)
            #pragma unroll 4
            for (int it = 0; it < 256; ++it) {
                x0 = fmaf(x0, aa, cc);
                x1 = fmaf(x1, aa, cc);
                x2 = fmaf(x2, aa, cc);
                x3 = fmaf(x3, aa, cc);
                x4 = fmaf(x4, aa, cc);
                x5 = fmaf(x5, aa, cc);
                x6 = fmaf(x6, aa, cc);
                x7 = fmaf(x7, aa, cc);
            }
            asm volatile("" :: "v"(x0), "v"(x1), "v"(x2), "v"(x3),
                               "v"(x4), "v"(x5), "v"(x6), "v"(x7));
            int vv = 0;
            if (tid == 0) vv = atomicAdd(&gsync[0], 0);
            vv = __builtin_amdgcn_readfirstlane(vv);
            if (__syncthreads_or(vv >= 16)) break;        // events finished
        }
        return;                                           // exit before choice/write
    }

    if (b == 0) {
        // ================= events body (verified r6, verbatim) =================
        unsigned long long myPref[16];
        #pragma unroll
        for (int k = 0; k < 16; ++k) myPref[k] = pref[tid + 512 * k];

        #pragma unroll
        for (int k = 0; k < 16; ++k) {
            const int s = k * 8 + wave;
            const int c = (int)(myPref[k] >> 60);
            #pragma unroll
            for (int e = 0; e < N_EXP; ++e) {
                unsigned long long mm = __ballot(c == e);
                if (lane == e) segmask[e][s] = mm;
            }
        }
        __syncthreads();

        const int eA = wave, eB = wave + 8;
        int capA = CAP, capB = CAP;
        unsigned long long m0A = 0, m1A = 0, m0B = 0, m1B = 0;
        int excl0A = 0, excl1A = 0, excl0B = 0, excl1B = 0;
        int segF = 0;
        unsigned long long mlep = 0;
        unsigned int avail = 0xFFFFu;
        int myp = 0, myf = 0;

        for (int round = 0; round < N_EXP; ++round) {
            // ---- capacity commit from previous round (scalar readlane; no-op at round 0) ----
            {
                const int sFs = __builtin_amdgcn_readfirstlane(segF);
                int exfA, exfB;
                unsigned long long mfA, mfB;
                if (sFs < 64) {
                    exfA = __builtin_amdgcn_readlane(excl0A, sFs);
                    exfB = __builtin_amdgcn_readlane(excl0B, sFs);
                    mfA  = rdlane64(m0A, sFs);
                    mfB  = rdlane64(m0B, sFs);
                } else {
                    exfA = __builtin_amdgcn_readlane(excl1A, sFs - 64);
                    exfB = __builtin_amdgcn_readlane(excl1B, sFs - 64);
                    mfA  = rdlane64(m1A, sFs - 64);
                    mfB  = rdlane64(m1B, sFs - 64);
                }
                capA -= exfA + (int)__popcll(mfA & mlep);
                capB -= exfB + (int)__popcll(mfB & mlep);
            }

            // ---- load masks + lazy in-register prune ----
            unsigned long long a0 = segmask[eA][lane];
            unsigned long long a1 = segmask[eA][64 + lane];
            unsigned long long b0 = segmask[eB][lane];
            unsigned long long b1 = segmask[eB][64 + lane];
            if (lane < segF)            { a0 = 0; b0 = 0; }
            else if (lane == segF)      { a0 &= ~mlep; b0 &= ~mlep; }
            if (64 + lane < segF)       { a1 = 0; b1 = 0; }
            else if (64 + lane == segF) { a1 &= ~mlep; b1 &= ~mlep; }
            m0A = a0; m1A = a1; m0B = b0; m1B = b1;

            // ---- 4 inclusive scans via DPP (integer-exact) ----
            const int c0A = (int)__popcll(a0), c1A = (int)__popcll(a1);
            const int c0B = (int)__popcll(b0), c1B = (int)__popcll(b1);
            const int v0A = wave_incl_scan(c0A, lane);
            const int v1A = wave_incl_scan(c1A, lane);
            const int v0B = wave_incl_scan(c0B, lane);
            const int v1B = wave_incl_scan(c1B, lane);
            const int tot0A = __builtin_amdgcn_readlane(v0A, 63);
            const int tot0B = __builtin_amdgcn_readlane(v0B, 63);
            excl0A = v0A - c0A;
            excl1A = tot0A + v1A - c1A;
            excl0B = v0B - c0B;
            excl1B = tot0B + v1B - c1B;

            // ---- crossing locate (expert A) ----
            int fpA = 0x7FFFFFFF;
            if ((avail >> eA) & 1u) {
                const int need = capA;
                int segc = -1, kk = 0;
                if (excl0A < need && excl0A + c0A >= need)      { segc = lane;      kk = need - excl0A; }
                else if (excl1A < need && excl1A + c1A >= need) { segc = 64 + lane; kk = need - excl1A; }
                unsigned long long bb = __ballot(segc >= 0);
                if (bb) {
                    const int l2    = __builtin_amdgcn_readfirstlane((int)__builtin_ctzll(bb));
                    const int sstar = __builtin_amdgcn_readlane(segc, l2);
                    const int k2    = __builtin_amdgcn_readlane(kk,   l2);
                    unsigned long long msel = (sstar < 64) ? rdlane64(a0, sstar)
                                                           : rdlane64(a1, sstar - 64);
                    int rr = (int)__popcll(msel & lt_mask);
                    bool hit = ((msel >> lane) & 1ull) && (rr == k2 - 1);
                    unsigned long long hb = __ballot(hit);
                    fpA = sstar * 64 + (int)__builtin_ctzll(hb);
                }
            }
            // ---- crossing locate (expert B) ----
            int fpB = 0x7FFFFFFF;
            if ((avail >> eB) & 1u) {
                const int need = capB;
                int segc = -1, kk = 0;
                if (excl0B < need && excl0B + c0B >= need)      { segc = lane;      kk = need - excl0B; }
                else if (excl1B < need && excl1B + c1B >= need) { segc = 64 + lane; kk = need - excl1B; }
                unsigned long long bb = __ballot(segc >= 0);
                if (bb) {
                    const int l2    = __builtin_amdgcn_readfirstlane((int)__builtin_ctzll(bb));
                    const int sstar = __builtin_amdgcn_readlane(segc, l2);
                    const int k2    = __builtin_amdgcn_readlane(kk,   l2);
                    unsigned long long msel = (sstar < 64) ? rdlane64(b0, sstar)
                                                           : rdlane64(b1, sstar - 64);
                    int rr = (int)__popcll(msel & lt_mask);
                    bool hit = ((msel >> lane) & 1ull) && (rr == k2 - 1);
                    unsigned long long hb = __ballot(hit);
                    fpB = sstar * 64 + (int)__builtin_ctzll(hb);
                }
            }
            if (lane == 0) { fparr[eA] = fpA; fparr[eB] = fpB; }
            __syncthreads();

            // ---- earliest fill event (redundant in all threads; same tie-break) ----
            int pmin = 0x7FFFFFFF, fe = 0;
            #pragma unroll
            for (int e = 0; e < N_EXP; ++e) {
                int f = fparr[e];
                if (f < pmin) { pmin = f; fe = e; }
            }
            if (tid == round) { myp = pmin; myf = fe; }

            const int nsegF = pmin >> 6;
            const unsigned long long nmlep = ((pmin & 63) == 63) ? ~0ull
                                             : ((1ull << ((pmin & 63) + 1)) - 1ull);
            const unsigned int navail = avail & ~(1u << fe);

            if (round < N_EXP - 1) {
                #pragma unroll
                for (int k = 0; k < 16; ++k) {
                    const int s = k * 8 + wave;
                    if (s >= nsegF) {
                        unsigned long long m = segmask[fe][s];
                        if (s == nsegF) m &= ~nmlep;
                        if ((m >> lane) & 1ull) {
                            unsigned long long pp = myPref[k];
                            int e2 = (int)(pp >> 60);
                            while (!((navail >> e2) & 1u)) { pp <<= 4; e2 = (int)(pp >> 60); }
                            atomicOr(&segmask[e2][s], 1ull << lane);
                        }
                    }
                }
            }
            segF = nsegF; mlep = nmlep; avail = navail;
            __syncthreads();
        }

        if (tid < N_EXP) {
            atomicExch(&evt[tid], myp);
            atomicExch(&evt[N_EXP + tid], myf);
        }
        // ================= end events body =================
    }

    // ---- grid barrier 1 (16 worker blocks; counter armed to 0 by K1) ----
    __syncthreads();
    if (tid == 0) {
        __threadfence();
        atomicAdd(&gsync[0], 1);
        while (atomicAdd(&gsync[0], 0) < 16) { __builtin_amdgcn_s_sleep(2); }
        __threadfence();
    }
    __syncthreads();

    // ---- choice phase: token t = b*512 + tid ----
    if (tid < N_EXP) evp[tid] = atomicAdd(&evt[tid], 0);
    else if (tid < 2 * N_EXP) evf[tid - N_EXP] = atomicAdd(&evt[tid], 0);
    __syncthreads();

    const int t = b * 512 + tid;
    unsigned int mask = 0xFFFFu;
    #pragma unroll
    for (int jj = 0; jj < N_EXP; ++jj)
        if (evp[jj] < t) mask &= ~(1u << evf[jj]);

    unsigned long long pp = pref[t];
    int e = (int)(pp >> 60);
    while (!((mask >> e) & 1u)) { pp <<= 4; e = (int)(pp >> 60); }

    unsigned long long own = 0ull;
    #pragma unroll
    for (int e2 = 0; e2 < N_EXP; ++e2) {
        unsigned long long mm = __ballot(e == e2);
        if (e == e2) own = mm;
        if (lane == e2) sc[wave][e2] = (int)__popcll(mm);
    }
    __syncthreads();

    if (tid < N_EXP) {
        int s = 0;
        #pragma unroll
        for (int w2 = 0; w2 < 8; ++w2) s += sc[w2][tid];
        atomicExch(&bcnt[b * N_EXP + tid], s);
    }

    // ---- grid barrier 2 ----
    __syncthreads();
    if (tid == 0) {
        __threadfence();
        atomicAdd(&gsync[1], 1);
        while (atomicAdd(&gsync[1], 0) < 16) { __builtin_amdgcn_s_sleep(2); }
        __threadfence();
    }
    __syncthreads();

    // ---- writeout phase: parallel gather of preceding blocks' counts ----
    for (int i = tid; i < b * N_EXP; i += 512)
        pcnt[i >> 4][i & 15] = atomicAdd(&bcnt[(i >> 4) * N_EXP + (i & 15)], 0);
    __syncthreads();
    if (tid < N_EXP) {
        int s = 0;
        for (int b2 = 0; b2 < b; ++b2) s += pcnt[b2][tid];
        base[tid] = s;
    }
    __syncthreads();

    int rank = (int)__popcll(own & lt_mask);
    for (int w2 = 0; w2 < wave; ++w2) rank += sc[w2][e];
    const int pos = base[e] + rank;
    out0[e * CAP + pos] = (float)t;
    out1[t] = probs[(size_t)t * N_EXP + e];
}

extern "C" void kernel_launch(void* const* d_in, const int* in_sizes, int n_in,
                              void* d_out, int out_size, void* d_ws, size_t ws_size,
                              hipStream_t stream) {
    const float* feat = (const float*)d_in[0];
    const float* W    = (const float*)d_in[1];
    const float* bias = (const float*)d_in[2];

    float* out = (float*)d_out;
    char*  ws  = (char*)d_ws;

    unsigned long long* pref = (unsigned long long*)(ws + 524288);
    float* probs             = (float*)(ws + 589824);
    int* evt                 = (int*)(ws + 1114112);
    int* gsync               = (int*)(ws + 1114240);
    int* bcnt                = (int*)(ws + 1122432);

    hipLaunchKernelGGL(gemm_finalize_kernel, dim3(T_TOK / 8), dim3(512), 0, stream,
                       feat, W, bias, pref, probs, gsync);
    hipLaunchKernelGGL(events_choice_write_kernel, dim3(256), dim3(512), 0, stream,
                       pref, probs, evt, gsync, bcnt, out, out + T_TOK);
}